// Round 8
// baseline (414.724 us; speedup 1.0000x reference)
//
#include <hip/hip_runtime.h>
#include <hip/hip_bf16.h>

#define B_    32
#define T_    256
#define C_    512
#define H_    512
#define TOUT_ 2048
#define TP_   258        // padded time length (zero row at t=0 and t=257)
#define K_    1536       // 3 * 512
#define EPS_  1e-5f

typedef __attribute__((ext_vector_type(8))) short bf16x8;
typedef __attribute__((ext_vector_type(4))) float f32x4;

#define GLL16(g, l)                                                        \
  __builtin_amdgcn_global_load_lds(                                        \
      (const __attribute__((address_space(1))) void*)(g),                  \
      (__attribute__((address_space(3))) void*)(l), 16, 0, 0)

// ---------------------------------------------------------------------------
// device-scope grid barrier (all 512 blocks co-resident by construction)
// ---------------------------------------------------------------------------
__device__ __forceinline__ void gbar(int* bar, int target) {
  // drain this wave's outstanding vmem (stores may be in flight past s_barrier)
  asm volatile("s_waitcnt vmcnt(0) lgkmcnt(0)" ::: "memory");
  __syncthreads();
  if (threadIdx.x == 0) {
    __threadfence();   // release: agent-scope writeback (cross-XCD visibility)
    __hip_atomic_fetch_add(bar, 1, __ATOMIC_RELEASE, __HIP_MEMORY_SCOPE_AGENT);
    while (__hip_atomic_load(bar, __ATOMIC_RELAXED, __HIP_MEMORY_SCOPE_AGENT) < target)
      __builtin_amdgcn_s_sleep(2);
    __threadfence();   // acquire: invalidate local L1/L2
  }
  __syncthreads();
}

// ---------------------------------------------------------------------------
// helpers
// ---------------------------------------------------------------------------
__device__ __forceinline__ void wt_convert_block(const float* __restrict__ W,
                                                 __hip_bfloat16* __restrict__ Wt,
                                                 int k0, int n0, int tid,
                                                 float* tile /* [32][33] */) {
  const int tx = tid & 31;
  const int ty = tid >> 5;
#pragma unroll
  for (int i = 0; i < 4; ++i)
    tile[(ty * 4 + i) * 33 + tx] = W[(size_t)(k0 + ty * 4 + i) * H_ + n0 + tx];
  __syncthreads();
#pragma unroll
  for (int i = 0; i < 4; ++i)
    Wt[(size_t)(n0 + ty * 4 + i) * K_ + k0 + tx] =
        __float2bfloat16(tile[tx * 33 + ty * 4 + i]);
}

// inclusive scan of one batch's 256 durations -> csum
__device__ __forceinline__ void csum_block(const int* __restrict__ dur,
                                           int* __restrict__ csum,
                                           int b, int tid, int* wsum) {
  int v = dur[b * T_ + tid];
#pragma unroll
  for (int off = 1; off < 64; off <<= 1) {
    int u = __shfl_up(v, off);
    if ((tid & 63) >= off) v += u;
  }
  if ((tid & 63) == 63) wsum[tid >> 6] = v;
  __syncthreads();
  int base = 0;
#pragma unroll
  for (int j = 0; j < 4; ++j)
    if (j < (tid >> 6)) base += wsum[j];
  csum[b * T_ + tid] = v + base;
}

// copy unit: 16 source rows; read row once, write its d output rows
__device__ __forceinline__ void expand_copy_block(const float* __restrict__ X,
                                                  const int* __restrict__ csum,
                                                  float* __restrict__ res,
                                                  int u, int tid) {
  const int wave = tid >> 6, lane = tid & 63;
#pragma unroll
  for (int k = 0; k < 4; ++k) {
    const int sr = u * 16 + wave * 4 + k;    // 0..8191
    const int b = sr >> 8, t = sr & 255;
    const int* cb = csum + b * T_;
    const int c0 = t ? cb[t - 1] : 0;
    const int d  = cb[t] - c0;
    if (d == 0) continue;
    const float* src = X + (size_t)sr * C_;
    const float4 v0 = *(const float4*)(src + lane * 4);
    const float4 v1 = *(const float4*)(src + 256 + lane * 4);
    float* dst = res + ((size_t)b * TOUT_ + c0) * C_;
    for (int j = 0; j < d; ++j) {
      *(float4*)(dst + (size_t)j * C_ + lane * 4)       = v0;
      *(float4*)(dst + (size_t)j * C_ + 256 + lane * 4) = v1;
    }
  }
}

// zero unit: 32 output rows of one batch, zero those >= total
__device__ __forceinline__ void expand_zero_block(const int* __restrict__ csum,
                                                  float* __restrict__ res,
                                                  int z, int tid) {
  const int b  = z >> 6;
  const int t0 = (z & 63) << 5;
  const int total = csum[b * T_ + 255];
  const float4 z4 = make_float4(0.f, 0.f, 0.f, 0.f);
  const int half = tid >> 7, c4 = tid & 127;
#pragma unroll
  for (int rr = half; rr < 32; rr += 2) {
    const int r = t0 + rr;
    if (r >= total)
      *(float4*)(res + ((size_t)b * TOUT_ + r) * C_ + c4 * 4) = z4;
  }
}

__device__ __forceinline__ void cvt_row(const float* __restrict__ X,
                                        __hip_bfloat16* __restrict__ xpad,
                                        __hip_bfloat16* __restrict__ hpad,
                                        int row, int c4) {
  const int b = row / TP_;
  const int t = row - b * TP_;
  const int c = c4 * 4;
  __hip_bfloat16* dst = xpad + (size_t)row * C_ + c;
  if (t == 0 || t == TP_ - 1) {
    ushort4 zz = make_ushort4(0, 0, 0, 0);
    *(ushort4*)dst = zz;
    *(ushort4*)(hpad + (size_t)row * C_ + c) = zz;
    return;
  }
  const float4 v = *(const float4*)(X + (size_t)(b * T_ + t - 1) * C_ + c);
  union { __hip_bfloat16 h[4]; ushort4 u; } o;
  o.h[0] = __float2bfloat16(v.x);
  o.h[1] = __float2bfloat16(v.y);
  o.h[2] = __float2bfloat16(v.z);
  o.h[3] = __float2bfloat16(v.w);
  *(ushort4*)dst = o.u;
}

// conv1d(k=3) tile: 64(M)x128(N), BK=32, 48 K-steps, 3-buf ring, counted vmcnt
__device__ __forceinline__ void conv_tile(const __hip_bfloat16* __restrict__ Apad,
                                          const __hip_bfloat16* __restrict__ Wt,
                                          const float* __restrict__ bias,
                                          float* __restrict__ Y,
                                          int bid, int tid,
                                          __hip_bfloat16 (*smA)[2048],
                                          __hip_bfloat16 (*smB)[4096]) {
  const int lane = tid & 63;
  const int wid  = tid >> 6;
  const int n0 = (bid & 3) << 7;
  const int m0 = (bid >> 2) << 6;
  const int b  = m0 >> 8;
  const int t0 = m0 & 255;
  const int wn = wid << 5;

  const int ra = tid & 63;
  const int ga = tid >> 6;
  const __hip_bfloat16* arow = Apad + (size_t)(b * TP_ + t0 + ra) * C_;
  const int rb = tid & 127;
  const int gb = tid >> 7;
  const __hip_bfloat16* brow = Wt + (size_t)(n0 + rb) * K_;

  f32x4 acc[4][2] = {};

  auto stage = [&](int buf, int k0) {
    const int kw = k0 >> 9;
    const int c0 = k0 & 511;
    GLL16(arow + kw * C_ + c0 + (ga << 3), &smA[buf][tid << 3]);
    GLL16(brow + k0 + (gb << 3), &smB[buf][tid << 3]);
    GLL16(brow + k0 + ((gb + 2) << 3), &smB[buf][(tid << 3) + 2048]);
  };

  auto compute = [&](int buf) {
    const __hip_bfloat16* As = smA[buf];
    const __hip_bfloat16* Bs = smB[buf];
    const int g   = lane >> 4;
    const int r15 = lane & 15;
    bf16x8 aF[4], bF[2];
#pragma unroll
    for (int i = 0; i < 4; ++i)
      aF[i] = *(const bf16x8*)(As + (g << 9) + (((i << 4) + r15) << 3));
#pragma unroll
    for (int i = 0; i < 2; ++i)
      bF[i] = *(const bf16x8*)(Bs + (g << 10) + ((wn + (i << 4) + r15) << 3));
#pragma unroll
    for (int mi = 0; mi < 4; ++mi)
#pragma unroll
      for (int ni = 0; ni < 2; ++ni)
        acc[mi][ni] = __builtin_amdgcn_mfma_f32_16x16x32_bf16(
            aF[mi], bF[ni], acc[mi][ni], 0, 0, 0);
  };

  // clean vmcnt baseline, then prefetch 3 tiles (9 vmem/wave in flight)
  asm volatile("s_waitcnt vmcnt(0)" ::: "memory");
  stage(0, 0);
  stage(1, 32);
  stage(2, 64);

  int buf = 0;
  for (int s = 0; s < 45; ++s) {
    asm volatile("s_waitcnt vmcnt(6)" ::: "memory");
    __builtin_amdgcn_sched_barrier(0);
    __builtin_amdgcn_s_barrier();
    compute(buf);
    asm volatile("s_waitcnt lgkmcnt(0)" ::: "memory");
    __builtin_amdgcn_s_barrier();
    stage(buf, (s + 3) << 5);
    buf = (buf == 2) ? 0 : buf + 1;
  }
  asm volatile("s_waitcnt vmcnt(6)" ::: "memory");
  __builtin_amdgcn_sched_barrier(0);
  __builtin_amdgcn_s_barrier();
  compute(buf);
  buf = (buf == 2) ? 0 : buf + 1;
  asm volatile("s_waitcnt vmcnt(3)" ::: "memory");
  __builtin_amdgcn_sched_barrier(0);
  __builtin_amdgcn_s_barrier();
  compute(buf);
  buf = (buf == 2) ? 0 : buf + 1;
  asm volatile("s_waitcnt vmcnt(0)" ::: "memory");
  __builtin_amdgcn_sched_barrier(0);
  __builtin_amdgcn_s_barrier();
  compute(buf);

  const int cn_base = n0 + wn + (lane & 15);
  const int rm_base = m0 + ((lane >> 4) << 2);
#pragma unroll
  for (int ni = 0; ni < 2; ++ni) {
    const int cn = cn_base + (ni << 4);
    const float bb = bias[cn];
#pragma unroll
    for (int mi = 0; mi < 4; ++mi) {
#pragma unroll
      for (int rq = 0; rq < 4; ++rq) {
        const int rm = rm_base + (mi << 4) + rq;
        Y[(size_t)rm * H_ + cn] = acc[mi][ni][rq] + bb;
      }
    }
  }
}

// LayerNorm(+ReLU) of one row -> bf16 padded layout
__device__ __forceinline__ void ln_relu_row(const float* __restrict__ in,
                                            const float* __restrict__ g,
                                            const float* __restrict__ beta,
                                            __hip_bfloat16* __restrict__ outpad,
                                            int row, int lane) {
  const float* r = in + (size_t)row * H_;
  const float4 v0 = *(const float4*)(r + lane * 4);
  const float4 v1 = *(const float4*)(r + 256 + lane * 4);

  float s = v0.x + v0.y + v0.z + v0.w + v1.x + v1.y + v1.z + v1.w;
  float q = v0.x * v0.x + v0.y * v0.y + v0.z * v0.z + v0.w * v0.w +
            v1.x * v1.x + v1.y * v1.y + v1.z * v1.z + v1.w * v1.w;
#pragma unroll
  for (int off = 32; off; off >>= 1) {
    s += __shfl_xor(s, off);
    q += __shfl_xor(q, off);
  }
  const float mu  = s * (1.0f / 512.0f);
  const float var = q * (1.0f / 512.0f) - mu * mu;
  const float rs  = rsqrtf(var + EPS_);

  const float4 g0 = *(const float4*)(g + lane * 4);
  const float4 g1 = *(const float4*)(g + 256 + lane * 4);
  const float4 e0 = *(const float4*)(beta + lane * 4);
  const float4 e1 = *(const float4*)(beta + 256 + lane * 4);

  union { __hip_bfloat16 h[4]; ushort4 u; } o0, o1;
  o0.h[0] = __float2bfloat16(fmaxf(0.f, (v0.x - mu) * rs * g0.x + e0.x));
  o0.h[1] = __float2bfloat16(fmaxf(0.f, (v0.y - mu) * rs * g0.y + e0.y));
  o0.h[2] = __float2bfloat16(fmaxf(0.f, (v0.z - mu) * rs * g0.z + e0.z));
  o0.h[3] = __float2bfloat16(fmaxf(0.f, (v0.w - mu) * rs * g0.w + e0.w));
  o1.h[0] = __float2bfloat16(fmaxf(0.f, (v1.x - mu) * rs * g1.x + e1.x));
  o1.h[1] = __float2bfloat16(fmaxf(0.f, (v1.y - mu) * rs * g1.y + e1.y));
  o1.h[2] = __float2bfloat16(fmaxf(0.f, (v1.z - mu) * rs * g1.z + e1.z));
  o1.h[3] = __float2bfloat16(fmaxf(0.f, (v1.w - mu) * rs * g1.w + e1.w));

  const int bq = row >> 8, t = row & 255;
  __hip_bfloat16* w = outpad + (size_t)(bq * TP_ + t + 1) * H_;
  *(ushort4*)(w + lane * 4)       = o0.u;
  *(ushort4*)(w + 256 + lane * 4) = o1.u;
}

// LayerNorm + ReLU + linear head of one row -> loglen[row]
__device__ __forceinline__ void ln_relu_linear_row(const float* __restrict__ in,
                                                   const float* __restrict__ g,
                                                   const float* __restrict__ beta,
                                                   const float* __restrict__ Wl,
                                                   const float* __restrict__ bl,
                                                   float* __restrict__ out,
                                                   int row, int lane) {
  const float* r = in + (size_t)row * H_;
  const float4 v0 = *(const float4*)(r + lane * 4);
  const float4 v1 = *(const float4*)(r + 256 + lane * 4);

  float s = v0.x + v0.y + v0.z + v0.w + v1.x + v1.y + v1.z + v1.w;
  float q = v0.x * v0.x + v0.y * v0.y + v0.z * v0.z + v0.w * v0.w +
            v1.x * v1.x + v1.y * v1.y + v1.z * v1.z + v1.w * v1.w;
#pragma unroll
  for (int off = 32; off; off >>= 1) {
    s += __shfl_xor(s, off);
    q += __shfl_xor(q, off);
  }
  const float mu  = s * (1.0f / 512.0f);
  const float var = q * (1.0f / 512.0f) - mu * mu;
  const float rs  = rsqrtf(var + EPS_);

  const float4 g0 = *(const float4*)(g + lane * 4);
  const float4 g1 = *(const float4*)(g + 256 + lane * 4);
  const float4 e0 = *(const float4*)(beta + lane * 4);
  const float4 e1 = *(const float4*)(beta + 256 + lane * 4);
  const float4 w0 = *(const float4*)(Wl + lane * 4);
  const float4 w1 = *(const float4*)(Wl + 256 + lane * 4);

  float sd = 0.f;
  sd += fmaxf(0.f, (v0.x - mu) * rs * g0.x + e0.x) * w0.x;
  sd += fmaxf(0.f, (v0.y - mu) * rs * g0.y + e0.y) * w0.y;
  sd += fmaxf(0.f, (v0.z - mu) * rs * g0.z + e0.z) * w0.z;
  sd += fmaxf(0.f, (v0.w - mu) * rs * g0.w + e0.w) * w0.w;
  sd += fmaxf(0.f, (v1.x - mu) * rs * g1.x + e1.x) * w1.x;
  sd += fmaxf(0.f, (v1.y - mu) * rs * g1.y + e1.y) * w1.y;
  sd += fmaxf(0.f, (v1.z - mu) * rs * g1.z + e1.z) * w1.z;
  sd += fmaxf(0.f, (v1.w - mu) * rs * g1.w + e1.w) * w1.w;
#pragma unroll
  for (int off = 32; off; off >>= 1) sd += __shfl_xor(sd, off);

  if (lane == 0) out[row] = sd + bl[0];
}

// ---------------------------------------------------------------------------
// THE mega-kernel: 512 blocks x 256 threads, all phases, grid barriers.
// ---------------------------------------------------------------------------
__global__ __launch_bounds__(256, 2) void mega_kernel(
    const float* __restrict__ X, const int* __restrict__ dur,
    const float* __restrict__ W1, const float* __restrict__ b1,
    const float* __restrict__ g1, const float* __restrict__ be1,
    const float* __restrict__ W2, const float* __restrict__ b2,
    const float* __restrict__ g2, const float* __restrict__ be2,
    const float* __restrict__ Wl, const float* __restrict__ bl,
    __hip_bfloat16* __restrict__ xpad, __hip_bfloat16* __restrict__ hpad,
    __hip_bfloat16* __restrict__ Wt1, __hip_bfloat16* __restrict__ Wt2,
    float* __restrict__ tmp, int* __restrict__ csum, int* __restrict__ ctrl,
    float* __restrict__ res, float* __restrict__ loglen) {
  __shared__ __hip_bfloat16 smA[3][2048];   // 12 KB
  __shared__ __hip_bfloat16 smB[3][4096];   // 24 KB
  __shared__ int s_unit;

  const int tid = threadIdx.x;
  const int bid = blockIdx.x;
  int* bar = ctrl;
  int* q1  = ctrl + 1;
  int* q2  = ctrl + 2;

  // ---------------- P0: prep ----------------
  if (bid < B_) csum_block(dur, csum, bid, tid, (int*)smB);
  __syncthreads();
  for (int t = bid; t < 1536; t += 512) {
    const bool isW1 = (t < 768);
    const int id = isW1 ? t : t - 768;       // 768 is NOT a power of two!
    if (isW1) wt_convert_block(W1, Wt1, (id % 48) * 32, (id / 48) * 32, tid, (float*)smA);
    else      wt_convert_block(W2, Wt2, (id % 48) * 32, (id / 48) * 32, tid, (float*)smA);
    __syncthreads();
  }
#pragma unroll
  for (int i = 0; i < 9; ++i) {
    const int row = i * 1024 + bid * 2 + (tid >> 7);
    if (row < B_ * TP_) cvt_row(X, xpad, hpad, row, tid & 127);
  }
  gbar(bar, 512);

  // ---------------- P1: conv1 + expand queue (512 copies + 768 zeros) -------
  conv_tile(xpad, Wt1, b1, tmp, bid, tid, smA, smB);
  while (true) {
    if (tid == 0)
      s_unit = __hip_atomic_fetch_add(q1, 1, __ATOMIC_RELAXED, __HIP_MEMORY_SCOPE_AGENT);
    __syncthreads();
    const int u = s_unit;
    __syncthreads();
    if (u >= 1280) break;
    if (u < 512) expand_copy_block(X, csum, res, u, tid);
    else         expand_zero_block(csum, res, u - 512, tid);
  }
  gbar(bar, 1024);

  // ---------------- P2: LN1 ----------------
  {
    const int wave = tid >> 6, lane = tid & 63;
#pragma unroll
    for (int i = 0; i < 4; ++i)
      ln_relu_row(tmp, g1, be1, hpad, bid * 16 + i * 4 + wave, lane);
  }
  gbar(bar, 1536);

  // ---------------- P3: conv2 + expand queue (zeros 768..2047) -------------
  conv_tile(hpad, Wt2, b2, tmp, bid, tid, smA, smB);
  while (true) {
    if (tid == 0)
      s_unit = __hip_atomic_fetch_add(q2, 1, __ATOMIC_RELAXED, __HIP_MEMORY_SCOPE_AGENT);
    __syncthreads();
    const int u = s_unit;
    __syncthreads();
    if (u >= 1280) break;
    expand_zero_block(csum, res, 768 + u, tid);
  }
  gbar(bar, 2048);

  // ---------------- P4: LN2 + linear ----------------
  {
    const int wave = tid >> 6, lane = tid & 63;
#pragma unroll
    for (int i = 0; i < 4; ++i)
      ln_relu_linear_row(tmp, g2, be2, Wl, bl, loglen, bid * 16 + i * 4 + wave, lane);
  }
}

// ---------------------------------------------------------------------------
extern "C" void kernel_launch(void* const* d_in, const int* in_sizes, int n_in,
                              void* d_out, int out_size, void* d_ws, size_t ws_size,
                              hipStream_t stream) {
  const float* x     = (const float*)d_in[0];
  const int*   dur   = (const int*)d_in[1];
  const float* W1    = (const float*)d_in[2];
  const float* b1    = (const float*)d_in[3];
  const float* g1    = (const float*)d_in[4];
  const float* beta1 = (const float*)d_in[5];
  const float* W2    = (const float*)d_in[6];
  const float* b2    = (const float*)d_in[7];
  const float* g2    = (const float*)d_in[8];
  const float* beta2 = (const float*)d_in[9];
  const float* Wl    = (const float*)d_in[10];
  const float* bl    = (const float*)d_in[11];

  float* out = (float*)d_out;
  float* res    = out;                              // [B, TOUT, C]
  float* loglen = out + (size_t)B_ * TOUT_ * C_;    // [B, T]

  char* ws = (char*)d_ws;
  __hip_bfloat16* xpad = (__hip_bfloat16*)ws;                       // 8.45 MB
  __hip_bfloat16* hpad = xpad + (size_t)B_ * TP_ * C_;              // 8.45 MB
  __hip_bfloat16* Wt1  = hpad + (size_t)B_ * TP_ * C_;              // 1.57 MB
  __hip_bfloat16* Wt2  = Wt1 + (size_t)H_ * K_;                     // 1.57 MB
  float* tmp  = (float*)(Wt2 + (size_t)H_ * K_);                    // 16.8 MB
  int*   csum = (int*)(tmp + (size_t)B_ * T_ * H_);                 // 32 KB
  int*   ctrl = csum + B_ * T_;                                     // 16 B

  hipMemsetAsync(ctrl, 0, 16, stream);

  mega_kernel<<<512, 256, 0, stream>>>(
      x, dur, W1, b1, g1, beta1, W2, b2, g2, beta2, Wl, bl,
      xpad, hpad, Wt1, Wt2, tmp, csum, ctrl, res, loglen);
}

// Round 9
// 120.812 us; speedup vs baseline: 3.4328x; 3.4328x over previous
//
#include <hip/hip_runtime.h>
#include <hip/hip_bf16.h>

#define B_    32
#define T_    256
#define C_    512
#define H_    512
#define TOUT_ 2048
#define TP_   258        // padded time length (zero row at t=0 and t=257)
#define K_    1536       // 3 * 512
#define EPS_  1e-5f

typedef __attribute__((ext_vector_type(8))) short bf16x8;
typedef __attribute__((ext_vector_type(4))) float f32x4;

#define GLL16(g, l)                                                        \
  __builtin_amdgcn_global_load_lds(                                        \
      (const __attribute__((address_space(1))) void*)(g),                  \
      (__attribute__((address_space(3))) void*)(l), 16, 0, 0)

// ---------------------------------------------------------------------------
// helpers shared by heterogeneous kernels
// ---------------------------------------------------------------------------
__device__ __forceinline__ void wt_convert_block(const float* __restrict__ W,
                                                 __hip_bfloat16* __restrict__ Wt,
                                                 int k0, int n0, int tid,
                                                 float* tile /* [32][33] */) {
  const int tx = tid & 31;
  const int ty = tid >> 5;
#pragma unroll
  for (int i = 0; i < 4; ++i)
    tile[(ty * 4 + i) * 33 + tx] = W[(size_t)(k0 + ty * 4 + i) * H_ + n0 + tx];
  __syncthreads();
#pragma unroll
  for (int i = 0; i < 4; ++i)
    Wt[(size_t)(n0 + ty * 4 + i) * K_ + k0 + tx] =
        __float2bfloat16(tile[tx * 33 + ty * 4 + i]);
}

// inclusive scan of one batch's 256 durations -> csum (2 barriers)
__device__ __forceinline__ void csum_block(const int* __restrict__ dur,
                                           int* __restrict__ csum,
                                           int b, int tid, int* wsum /*>=4 ints*/) {
  int v = dur[b * T_ + tid];
#pragma unroll
  for (int off = 1; off < 64; off <<= 1) {
    int u = __shfl_up(v, off);
    if ((tid & 63) >= off) v += u;
  }
  if ((tid & 63) == 63) wsum[tid >> 6] = v;
  __syncthreads();
  int base = 0;
#pragma unroll
  for (int j = 0; j < 4; ++j)
    if (j < (tid >> 6)) base += wsum[j];
  csum[b * T_ + tid] = v + base;
}

// copy block: 16 source rows; read row once, write its d output rows
__device__ __forceinline__ void expand_copy_block(const float* __restrict__ X,
                                                  const int* __restrict__ csum,
                                                  float* __restrict__ res,
                                                  int u, int tid) {
  const int wave = tid >> 6, lane = tid & 63;
#pragma unroll
  for (int k = 0; k < 4; ++k) {
    const int sr = u * 16 + wave * 4 + k;    // 0..8191
    const int b = sr >> 8, t = sr & 255;
    const int* cb = csum + b * T_;
    const int c0 = t ? cb[t - 1] : 0;
    const int d  = cb[t] - c0;
    if (d == 0) continue;
    const float* src = X + (size_t)sr * C_;
    const float4 v0 = *(const float4*)(src + lane * 4);
    const float4 v1 = *(const float4*)(src + 256 + lane * 4);
    float* dst = res + ((size_t)b * TOUT_ + c0) * C_;
    for (int j = 0; j < d; ++j) {
      *(float4*)(dst + (size_t)j * C_ + lane * 4)       = v0;
      *(float4*)(dst + (size_t)j * C_ + 256 + lane * 4) = v1;
    }
  }
}

// zero block: 32 output rows of one batch, zero those >= total
__device__ __forceinline__ void expand_zero_block(const int* __restrict__ csum,
                                                  float* __restrict__ res,
                                                  int z, int tid) {
  const int b  = z >> 6;
  const int t0 = (z & 63) << 5;
  const int total = csum[b * T_ + 255];
  const float4 z4 = make_float4(0.f, 0.f, 0.f, 0.f);
  const int half = tid >> 7, c4 = tid & 127;
#pragma unroll
  for (int rr = half; rr < 32; rr += 2) {
    const int r = t0 + rr;
    if (r >= total)
      *(float4*)(res + ((size_t)b * TOUT_ + r) * C_ + c4 * 4) = z4;
  }
}

// ---------------------------------------------------------------------------
// 1) prep: cvt_x_pad (0..4127) + cvt W1 (4128..4895) + csum (4896..4927)
// ---------------------------------------------------------------------------
__global__ __launch_bounds__(256) void prep_kernel(const float* __restrict__ X,
                                                   const float* __restrict__ W1,
                                                   const int* __restrict__ dur,
                                                   __hip_bfloat16* __restrict__ xpad,
                                                   __hip_bfloat16* __restrict__ hpad,
                                                   __hip_bfloat16* __restrict__ Wt1,
                                                   int* __restrict__ csum) {
  __shared__ float tile[32 * 33];
  const int tid = threadIdx.x;
  if (blockIdx.x >= 4896) {
    csum_block(dur, csum, blockIdx.x - 4896, tid, (int*)tile);
    return;
  }
  if (blockIdx.x >= 4128) {
    const int id = blockIdx.x - 4128;       // 0..767
    wt_convert_block(W1, Wt1, (id % 48) * 32, (id / 48) * 32, tid, tile);
    return;
  }
  const int row = blockIdx.x * 2 + (tid >> 7);   // 0..8255
  const int b = row / TP_;
  const int t = row - b * TP_;
  const int c = (tid & 127) * 4;
  __hip_bfloat16* dst = xpad + (size_t)row * C_ + c;
  if (t == 0 || t == TP_ - 1) {
    ushort4 zz = make_ushort4(0, 0, 0, 0);
    *(ushort4*)dst = zz;
    *(ushort4*)(hpad + (size_t)row * C_ + c) = zz;
    return;
  }
  const float4 v = *(const float4*)(X + (size_t)(b * T_ + t - 1) * C_ + c);
  union { __hip_bfloat16 h[4]; ushort4 u; } o;
  o.h[0] = __float2bfloat16(v.x);
  o.h[1] = __float2bfloat16(v.y);
  o.h[2] = __float2bfloat16(v.z);
  o.h[3] = __float2bfloat16(v.w);
  *(ushort4*)dst = o.u;
}

// ---------------------------------------------------------------------------
// 2) heterogeneous: conv GEMM (0..511) || expand units (512..1791)
//    || optional W2 transpose (1792..2559, first dispatch only)
//    conv: 64(M)x128(N) tile, BK=64, 24 K-steps, 3-buf LDS ring (72 KB),
//    counted vmcnt(12) pipeline: 6 GLL16/thread/stage, depth-3 prefetch,
//    16 MFMA/wave/step. Never drains vmcnt to 0 in the main loop.
//    LDS elem layout per buf: A [slab2][g4][row64][8], B [slab2][g4][row128][8]
// ---------------------------------------------------------------------------
__global__ __launch_bounds__(256) void conv_expand_kernel(
    const __hip_bfloat16* __restrict__ Apad,   // [32*258, 512]
    const __hip_bfloat16* __restrict__ Wt,     // [512, 1536]
    const float* __restrict__ bias,            // [512]
    float* __restrict__ Y,                     // [8192, 512]
    const float* __restrict__ X,               // f32 input (for expand)
    const int* __restrict__ csum,
    float* __restrict__ res,
    const float* __restrict__ W2,              // may be null
    __hip_bfloat16* __restrict__ Wt2,          // may be null
    int ex_base) {
  __shared__ __hip_bfloat16 smA[3][4096];      // 24 KB
  __shared__ __hip_bfloat16 smB[3][8192];      // 48 KB

  const int tid = threadIdx.x;

  if (blockIdx.x >= 1792) {                    // W2 transpose ride-along
    const int id = blockIdx.x - 1792;          // 0..767
    wt_convert_block(W2, Wt2, (id % 48) * 32, (id / 48) * 32, tid, (float*)smA);
    return;
  }
  if (blockIdx.x >= 512) {                     // expand ride-along
    const int u = ex_base + (blockIdx.x - 512);
    if (u < 512) expand_copy_block(X, csum, res, u, tid);
    else         expand_zero_block(csum, res, u - 512, tid);
    return;
  }

  // ---- conv GEMM path ----
  const int lane = tid & 63;
  const int wid  = tid >> 6;
  const int cid  = blockIdx.x;
  const int n0 = (cid & 3) << 7;
  const int m0 = (cid >> 2) << 6;
  const int b  = m0 >> 8;
  const int t0 = m0 & 255;
  const int wn = wid << 5;

  // A staging: 2 GLL16/thread (slab0, slab1); row ra, k-group ga
  const int ra = tid & 63;
  const int ga = tid >> 6;                     // 0..3
  const __hip_bfloat16* arow = Apad + (size_t)(b * TP_ + t0 + ra) * C_;
  // B staging: 4 GLL16/thread; row rb, k-groups gb & gb+2, both slabs
  const int rb = tid & 127;
  const int gb = tid >> 7;                     // 0..1
  const __hip_bfloat16* brow = Wt + (size_t)(n0 + rb) * K_;

  f32x4 acc[4][2] = {};

  // BK=64 never straddles a kw window (512 % 64 == 0)
  auto stage = [&](int buf, int k0) {
    const int kw = k0 >> 9;
    const int c0 = k0 & 511;
    const __hip_bfloat16* ag = arow + kw * C_ + c0 + (ga << 3);
    __hip_bfloat16* al = &smA[buf][(ga << 9) + (ra << 3)];
    GLL16(ag, al);                             // slab 0
    GLL16(ag + 32, al + 2048);                 // slab 1 (k+32)
    const __hip_bfloat16* bg = brow + k0 + (gb << 3);
    __hip_bfloat16* bl = &smB[buf][(gb << 10) + (rb << 3)];
    GLL16(bg, bl);                             // slab0, g=gb
    GLL16(bg + 16, bl + 2048);                 // slab0, g=gb+2
    GLL16(bg + 32, bl + 4096);                 // slab1, g=gb
    GLL16(bg + 48, bl + 6144);                 // slab1, g=gb+2
  };

  auto compute = [&](int bufi) {
    const int g   = lane >> 4;
    const int r15 = lane & 15;
#pragma unroll
    for (int sl = 0; sl < 2; ++sl) {
      const __hip_bfloat16* As = &smA[bufi][sl << 11];
      const __hip_bfloat16* Bs = &smB[bufi][sl << 12];
      bf16x8 aF[4], bF[2];
#pragma unroll
      for (int i = 0; i < 4; ++i)
        aF[i] = *(const bf16x8*)(As + (g << 9) + (((i << 4) + r15) << 3));
#pragma unroll
      for (int i = 0; i < 2; ++i)
        bF[i] = *(const bf16x8*)(Bs + (g << 10) + ((wn + (i << 4) + r15) << 3));
#pragma unroll
      for (int mi = 0; mi < 4; ++mi)
#pragma unroll
        for (int ni = 0; ni < 2; ++ni)
          acc[mi][ni] = __builtin_amdgcn_mfma_f32_16x16x32_bf16(
              aF[mi], bF[ni], acc[mi][ni], 0, 0, 0);
    }
  };

  // prologue: clean vmcnt baseline, prefetch 3 tiles (18 vmem/wave in flight)
  asm volatile("s_waitcnt vmcnt(0)" ::: "memory");
  stage(0, 0);
  stage(1, 64);
  stage(2, 128);

  int buf = 0;
  // main loop: compute tiles 0..20, stage tiles 3..23 (k0 = tile*64)
  for (int s = 0; s < 21; ++s) {
    asm volatile("s_waitcnt vmcnt(12)" ::: "memory");  // oldest tile's 6 loads done
    __builtin_amdgcn_sched_barrier(0);
    __builtin_amdgcn_s_barrier();
    compute(buf);
    asm volatile("s_waitcnt lgkmcnt(0)" ::: "memory");
    __builtin_amdgcn_s_barrier();
    stage(buf, (s + 3) << 6);
    buf = (buf == 2) ? 0 : buf + 1;
  }
  // tail: tiles 21,22,23 — drain 12 -> 6 -> 0
  asm volatile("s_waitcnt vmcnt(12)" ::: "memory");
  __builtin_amdgcn_sched_barrier(0);
  __builtin_amdgcn_s_barrier();
  compute(buf);
  buf = (buf == 2) ? 0 : buf + 1;
  asm volatile("s_waitcnt vmcnt(6)" ::: "memory");
  __builtin_amdgcn_sched_barrier(0);
  __builtin_amdgcn_s_barrier();
  compute(buf);
  buf = (buf == 2) ? 0 : buf + 1;
  asm volatile("s_waitcnt vmcnt(0)" ::: "memory");
  __builtin_amdgcn_sched_barrier(0);
  __builtin_amdgcn_s_barrier();
  compute(buf);

  // epilogue: C/D layout col = lane&15 (n), row = (lane>>4)*4 + reg (m)
  const int cn_base = n0 + wn + (lane & 15);
  const int rm_base = m0 + ((lane >> 4) << 2);
#pragma unroll
  for (int ni = 0; ni < 2; ++ni) {
    const int cn = cn_base + (ni << 4);
    const float bb = bias[cn];
#pragma unroll
    for (int mi = 0; mi < 4; ++mi) {
#pragma unroll
      for (int rq = 0; rq < 4; ++rq) {
        const int rm = rm_base + (mi << 4) + rq;
        Y[(size_t)rm * H_ + cn] = acc[mi][ni][rq] + bb;
      }
    }
  }
}

// ---------------------------------------------------------------------------
// 3) LayerNorm + ReLU, f32 in -> bf16 out written into padded layout
// ---------------------------------------------------------------------------
__global__ __launch_bounds__(256) void ln_relu_pad_kernel(const float* __restrict__ in,
                                                          const float* __restrict__ g,
                                                          const float* __restrict__ beta,
                                                          __hip_bfloat16* __restrict__ outpad) {
  const int wave = threadIdx.x >> 6;
  const int lane = threadIdx.x & 63;
  const int row  = blockIdx.x * 4 + wave;   // 0..8191
  const float* r = in + (size_t)row * H_;

  const float4 v0 = *(const float4*)(r + lane * 4);
  const float4 v1 = *(const float4*)(r + 256 + lane * 4);

  float s = v0.x + v0.y + v0.z + v0.w + v1.x + v1.y + v1.z + v1.w;
  float q = v0.x * v0.x + v0.y * v0.y + v0.z * v0.z + v0.w * v0.w +
            v1.x * v1.x + v1.y * v1.y + v1.z * v1.z + v1.w * v1.w;
#pragma unroll
  for (int off = 32; off; off >>= 1) {
    s += __shfl_xor(s, off);
    q += __shfl_xor(q, off);
  }
  const float mu  = s * (1.0f / 512.0f);
  const float var = q * (1.0f / 512.0f) - mu * mu;
  const float rs  = rsqrtf(var + EPS_);

  const float4 g0 = *(const float4*)(g + lane * 4);
  const float4 g1 = *(const float4*)(g + 256 + lane * 4);
  const float4 e0 = *(const float4*)(beta + lane * 4);
  const float4 e1 = *(const float4*)(beta + 256 + lane * 4);

  union { __hip_bfloat16 h[4]; ushort4 u; } o0, o1;
  o0.h[0] = __float2bfloat16(fmaxf(0.f, (v0.x - mu) * rs * g0.x + e0.x));
  o0.h[1] = __float2bfloat16(fmaxf(0.f, (v0.y - mu) * rs * g0.y + e0.y));
  o0.h[2] = __float2bfloat16(fmaxf(0.f, (v0.z - mu) * rs * g0.z + e0.z));
  o0.h[3] = __float2bfloat16(fmaxf(0.f, (v0.w - mu) * rs * g0.w + e0.w));
  o1.h[0] = __float2bfloat16(fmaxf(0.f, (v1.x - mu) * rs * g1.x + e1.x));
  o1.h[1] = __float2bfloat16(fmaxf(0.f, (v1.y - mu) * rs * g1.y + e1.y));
  o1.h[2] = __float2bfloat16(fmaxf(0.f, (v1.z - mu) * rs * g1.z + e1.z));
  o1.h[3] = __float2bfloat16(fmaxf(0.f, (v1.w - mu) * rs * g1.w + e1.w));

  const int bq = row >> 8, t = row & 255;
  __hip_bfloat16* w = outpad + (size_t)(bq * TP_ + t + 1) * H_;
  *(ushort4*)(w + lane * 4)       = o0.u;
  *(ushort4*)(w + 256 + lane * 4) = o1.u;
}

// ---------------------------------------------------------------------------
// 4) LayerNorm + ReLU + linear head fused
// ---------------------------------------------------------------------------
__global__ __launch_bounds__(256) void ln_relu_linear_kernel(const float* __restrict__ in,
                                                             const float* __restrict__ g,
                                                             const float* __restrict__ beta,
                                                             const float* __restrict__ Wl,
                                                             const float* __restrict__ bl,
                                                             float* __restrict__ out) {
  const int wave = threadIdx.x >> 6;
  const int lane = threadIdx.x & 63;
  const int row  = blockIdx.x * 4 + wave;
  const float* r = in + (size_t)row * H_;

  const float4 v0 = *(const float4*)(r + lane * 4);
  const float4 v1 = *(const float4*)(r + 256 + lane * 4);

  float s = v0.x + v0.y + v0.z + v0.w + v1.x + v1.y + v1.z + v1.w;
  float q = v0.x * v0.x + v0.y * v0.y + v0.z * v0.z + v0.w * v0.w +
            v1.x * v1.x + v1.y * v1.y + v1.z * v1.z + v1.w * v1.w;
#pragma unroll
  for (int off = 32; off; off >>= 1) {
    s += __shfl_xor(s, off);
    q += __shfl_xor(q, off);
  }
  const float mu  = s * (1.0f / 512.0f);
  const float var = q * (1.0f / 512.0f) - mu * mu;
  const float rs  = rsqrtf(var + EPS_);

  const float4 g0 = *(const float4*)(g + lane * 4);
  const float4 g1 = *(const float4*)(g + 256 + lane * 4);
  const float4 e0 = *(const float4*)(beta + lane * 4);
  const float4 e1 = *(const float4*)(beta + 256 + lane * 4);
  const float4 w0 = *(const float4*)(Wl + lane * 4);
  const float4 w1 = *(const float4*)(Wl + 256 + lane * 4);

  float sd = 0.f;
  sd += fmaxf(0.f, (v0.x - mu) * rs * g0.x + e0.x) * w0.x;
  sd += fmaxf(0.f, (v0.y - mu) * rs * g0.y + e0.y) * w0.y;
  sd += fmaxf(0.f, (v0.z - mu) * rs * g0.z + e0.z) * w0.z;
  sd += fmaxf(0.f, (v0.w - mu) * rs * g0.w + e0.w) * w0.w;
  sd += fmaxf(0.f, (v1.x - mu) * rs * g1.x + e1.x) * w1.x;
  sd += fmaxf(0.f, (v1.y - mu) * rs * g1.y + e1.y) * w1.y;
  sd += fmaxf(0.f, (v1.z - mu) * rs * g1.z + e1.z) * w1.z;
  sd += fmaxf(0.f, (v1.w - mu) * rs * g1.w + e1.w) * w1.w;
#pragma unroll
  for (int off = 32; off; off >>= 1) sd += __shfl_xor(sd, off);

  if (lane == 0) out[row] = sd + bl[0];
}

// ---------------------------------------------------------------------------
extern "C" void kernel_launch(void* const* d_in, const int* in_sizes, int n_in,
                              void* d_out, int out_size, void* d_ws, size_t ws_size,
                              hipStream_t stream) {
  const float* x     = (const float*)d_in[0];
  const int*   dur   = (const int*)d_in[1];
  const float* W1    = (const float*)d_in[2];
  const float* b1    = (const float*)d_in[3];
  const float* g1    = (const float*)d_in[4];
  const float* beta1 = (const float*)d_in[5];
  const float* W2    = (const float*)d_in[6];
  const float* b2    = (const float*)d_in[7];
  const float* g2    = (const float*)d_in[8];
  const float* beta2 = (const float*)d_in[9];
  const float* Wl    = (const float*)d_in[10];
  const float* bl    = (const float*)d_in[11];

  float* out = (float*)d_out;
  float* res    = out;                              // [B, TOUT, C]
  float* loglen = out + (size_t)B_ * TOUT_ * C_;    // [B, T]

  char* ws = (char*)d_ws;
  __hip_bfloat16* xpad = (__hip_bfloat16*)ws;                       // 8.45 MB
  __hip_bfloat16* hpad = xpad + (size_t)B_ * TP_ * C_;              // 8.45 MB
  __hip_bfloat16* Wt1  = hpad + (size_t)B_ * TP_ * C_;              // 1.57 MB
  __hip_bfloat16* Wt2  = Wt1 + (size_t)H_ * K_;                     // 1.57 MB
  float* tmp1 = (float*)(Wt2 + (size_t)H_ * K_);                    // 16.8 MB
  int*   csum = (int*)(tmp1 + (size_t)B_ * T_ * H_);                // 32 KB

  prep_kernel<<<4928, 256, 0, stream>>>(x, W1, dur, xpad, hpad, Wt1, csum);

  // conv1 || expand units 0..1279 (all copies + zeros 0..767) || W2 transpose
  conv_expand_kernel<<<2560, 256, 0, stream>>>(xpad, Wt1, b1, tmp1,
                                               x, csum, res, W2, Wt2, 0);
  ln_relu_pad_kernel<<<B_ * T_ / 4, 256, 0, stream>>>(tmp1, g1, beta1, hpad);

  // conv2 || expand units 1280..2559 (zeros 768..2047)
  conv_expand_kernel<<<1792, 256, 0, stream>>>(hpad, Wt2, b2, tmp1,
                                               x, csum, res, nullptr, nullptr, 1280);
  ln_relu_linear_kernel<<<B_ * T_ / 4, 256, 0, stream>>>(tmp1, g2, beta2, Wl, bl, loglen);
}